// Round 10
// baseline (42.759 us; speedup 1.0000x reference)
//
#include <hip/hip_runtime.h>

#define RCUT 6.0f

typedef _Float16 h2v __attribute__((ext_vector_type(2)));
typedef _Float16 h8  __attribute__((ext_vector_type(8)));
typedef float    f4  __attribute__((ext_vector_type(4)));

__device__ __forceinline__ float fast_tanh(float x) {
    float e = __expf(2.0f * x);              // inf for large x -> tanh=1
    return 1.0f - 2.0f * __builtin_amdgcn_rcpf(e + 1.0f);
}

__device__ __forceinline__ h2v pkh(float a, float b) {
#if __has_builtin(__builtin_amdgcn_cvt_pkrtz)
    union { __fp16 __attribute__((ext_vector_type(2))) r; h2v h; } u;
    u.r = __builtin_amdgcn_cvt_pkrtz(a, b);
    return u.h;
#else
    h2v r; r.x = (_Float16)a; r.y = (_Float16)b; return r;
#endif
}

// ---- Kernel 1: 2 atoms/block; barrier-free per-wave MLP chunks -------------
// Blocks [0, NB): atom pair. Blocks [NB, NB+288): fit-weight transpose prep.
__global__ __launch_bounds__(256, 3) void k_embed(
    const float* __restrict__ coord, const float* __restrict__ box,
    const float* __restrict__ srmean, const float* __restrict__ srstd,
    const float* __restrict__ xrsrstd, const float* __restrict__ Gbias,
    const float* __restrict__ eW0, const float* __restrict__ eb0,
    const float* __restrict__ eW1, const float* __restrict__ eb1,
    const float* __restrict__ eW2, const float* __restrict__ eb2,
    const int* __restrict__ n1p,
    const float* __restrict__ fW0, const float* __restrict__ fW1,
    h2v* __restrict__ feat, _Float16* __restrict__ W0ht,
    _Float16* __restrict__ W1ht, unsigned int* __restrict__ counter, int N)
{
    const int nb  = blockIdx.x;
    const int tid = threadIdx.x;
    const int NB  = N >> 1;

    __shared__ float s_srn[1024];                        // 4 KB
    __shared__ __align__(16) float s_cf[4][1024];        // 16 KB (f32 coefs)
    __shared__ unsigned short s_nbr[1024];               // 2 KB
    __shared__ __align__(16) _Float16 s_h1w[4][16][36];  // 4.5 KB per-wave scratch
    __shared__ float s_gA[4][4][64];                     // 4 KB
    __shared__ float s_gB[4][4][64];                     // 4 KB
    __shared__ float s_g4[2][256];                       // 2 KB
    __shared__ int s_wA[4], s_wB[4];

    // ================= prep path: transpose+fp16 fit weights =================
    if (nb >= NB) {
        const int b = nb - NB;
        if (b == 0 && tid == 0) *counter = 0u;
        float (*s_t)[33] = reinterpret_cast<float(*)[33]>(&s_cf[0][0]);
        if (b < 256) {
            int type = b >> 7, tb = b & 127;
            int ki = tb >> 2, ci = tb & 3;
            const float* src = fW0 + (size_t)type * 131072;
            int c = tid & 31, r0 = (tid >> 5) * 4;
            #pragma unroll
            for (int q = 0; q < 4; q++)
                s_t[r0 + q][c] = src[(size_t)(ki * 32 + r0 + q) * 128 + ci * 32 + c];
            __syncthreads();
            _Float16* dst = W0ht + (size_t)type * 131072;
            int kk = tid & 31, c0 = (tid >> 5) * 4;
            #pragma unroll
            for (int q = 0; q < 4; q++)
                dst[(size_t)(ci * 32 + c0 + q) * 1024 + ki * 32 + kk] = (_Float16)s_t[kk][c0 + q];
        } else {
            int b2v = b - 256, type = b2v >> 4, tb = b2v & 15;
            int ki = tb >> 2, ci = tb & 3;
            const float* src = fW1 + (size_t)type * 16384;
            int c = tid & 31, r0 = (tid >> 5) * 4;
            #pragma unroll
            for (int q = 0; q < 4; q++)
                s_t[r0 + q][c] = src[(size_t)(ki * 32 + r0 + q) * 128 + ci * 32 + c];
            __syncthreads();
            _Float16* dst = W1ht + (size_t)type * 16384;
            int kk = tid & 31, c0 = (tid >> 5) * 4;
            #pragma unroll
            for (int q = 0; q < 4; q++)
                dst[(size_t)(ci * 32 + c0 + q) * 128 + ki * 32 + kk] = (_Float16)s_t[kk][c0 + q];
        }
        return;
    }

    // ================= main path =================
    const int nA = 2 * nb, nBt = 2 * nb + 1;
    const int n1 = *n1p;
    const int ti = (nA >= n1) ? 1 : 0;
    const int wid = tid >> 6, lane = tid & 63;
    const int l15 = lane & 15, lk = lane >> 4;

    // ---- register fragments (loads pipeline; proven fine in R7) ----
    h8 w0h[2], b0h[2];                 // h0 net: lane covers f = 8lk+q (lk<2)
    #pragma unroll
    for (int j = 0; j < 2; j++) {
        h8 wv = {}, bv = {};
        if (lk < 2) {
            #pragma unroll
            for (int q = 0; q < 8; q++) {
                wv[q] = (_Float16)eW0[(2 * ti + j) * 16 + 8 * lk + q];
                bv[q] = (_Float16)eb0[(2 * ti + j) * 16 + 8 * lk + q];
            }
        }
        w0h[j] = wv; b0h[j] = bv;
    }
    h8 w1f[2][2];                      // W1 B-frags, K 16 padded to 32
    float b1r[2][2];
    #pragma unroll
    for (int j = 0; j < 2; j++) {
        const float* w1g = eW1 + (size_t)(2 * ti + j) * 512;
        #pragma unroll
        for (int nt1 = 0; nt1 < 2; nt1++) {
            h8 v = {};
            if (lk < 2) {
                #pragma unroll
                for (int r = 0; r < 8; r++)
                    v[r] = (_Float16)w1g[(8 * lk + r) * 32 + 16 * nt1 + l15];
            }
            w1f[j][nt1] = v;
            b1r[j][nt1] = eb1[(2 * ti + j) * 32 + 16 * nt1 + l15];
        }
    }
    h8 w2f[2][4];                      // W2 B-frags
    float b2r[2][4];
    #pragma unroll
    for (int j = 0; j < 2; j++) {
        const float* w2g = eW2 + (size_t)(2 * ti + j) * 2048;
        #pragma unroll
        for (int nt = 0; nt < 4; nt++) {
            h8 v;
            #pragma unroll
            for (int r = 0; r < 8; r++)
                v[r] = (_Float16)w2g[(8 * lk + r) * 64 + 16 * nt + l15];
            w2f[j][nt] = v;
            b2r[j][nt] = eb2[(2 * ti + j) * 64 + 16 * nt + l15];
        }
    }

    const float Lx = box[0], Ly = box[4], Lz = box[8];
    const float iLx = 1.0f / Lx, iLy = 1.0f / Ly, iLz = 1.0f / Lz;
    const float xA = coord[nA], yA = coord[N + nA], zA = coord[2 * N + nA];
    const float xB = coord[nBt], yB = coord[N + nBt], zB = coord[2 * N + nBt];
    const float srm  = srmean[ti];
    const float isrs = 1.0f / srstd[ti];
    const float ixrs = 1.0f / xrsrstd[ti];

    // ---- dual-center scan pass 1 ----
    unsigned long long balA[4], balB[4];
    float dxA[4], dyA[4], dzA[4], r2A[4];
    float dxB[4], dyB[4], dzB[4], r2B[4];
    {
        int wA = 0, wB = 0;
        const int mystart = wid * 256;
        #pragma unroll
        for (int r = 0; r < 4; r++) {
            int m = mystart + r * 64 + lane;
            float x = coord[m], y = coord[N + m], z = coord[2 * N + m];
            float ax = x - xA; ax -= Lx * rintf(ax * iLx);
            float ay = y - yA; ay -= Ly * rintf(ay * iLy);
            float az = z - zA; az -= Lz * rintf(az * iLz);
            float ra = ax * ax + ay * ay + az * az;
            float bx = x - xB; bx -= Lx * rintf(bx * iLx);
            float by = y - yB; by -= Ly * rintf(by * iLy);
            float bz = z - zB; bz -= Lz * rintf(bz * iLz);
            float rb = bx * bx + by * by + bz * bz;
            dxA[r] = ax; dyA[r] = ay; dzA[r] = az; r2A[r] = ra;
            dxB[r] = bx; dyB[r] = by; dzB[r] = bz; r2B[r] = rb;
            bool pA = (ra < RCUT * RCUT) && (m != nA);
            bool pB = (rb < RCUT * RCUT) && (m != nBt);
            balA[r] = __ballot(pA);
            balB[r] = __ballot(pB);
            wA += (int)__popcll(balA[r]);
            wB += (int)__popcll(balB[r]);
        }
        if (lane == 0) { s_wA[wid] = wA; s_wB[wid] = wB; }
    }
    __syncthreads();
    int cntA = s_wA[0] + s_wA[1] + s_wA[2] + s_wA[3];
    int cntB = s_wB[0] + s_wB[1] + s_wB[2] + s_wB[3];
    if (cntA > 512) cntA = 512;
    const int cntA_pad = (cntA + 15) & ~15;
    if (cntB > 1024 - cntA_pad) cntB = 1024 - cntA_pad;
    const int cntB_pad = (cntB + 15) & ~15;
    const int nchunks = (cntA_pad + cntB_pad) >> 4;

    // ---- zero-fill pair arrays (pads & tails read as zero coef) ----
    {
        f4 z = {0.f, 0.f, 0.f, 0.f};
        *(f4*)&s_srn[tid * 4] = z;
        #pragma unroll
        for (int k = 0; k < 4; k++) *(f4*)&s_cf[k][tid * 4] = z;
        *(unsigned long long*)&s_nbr[tid * 4] = 0ull;
    }
    __syncthreads();

    // ---- scan pass 2: write pair data (A at 0, B at cntA_pad) ----
    {
        int baseA = 0, baseB = cntA_pad;
        for (int w = 0; w < wid; w++) { baseA += s_wA[w]; baseB += s_wB[w]; }
        const unsigned long long lt = (1ull << lane) - 1ull;
        const int mystart = wid * 256;
        #pragma unroll
        for (int r = 0; r < 4; r++) {
            int m = mystart + r * 64 + lane;
            #pragma unroll
            for (int cc = 0; cc < 2; cc++) {
                unsigned long long bal = cc ? balB[r] : balA[r];
                int base = cc ? baseB : baseA;
                int lim  = cc ? (cntA_pad + cntB) : cntA;
                if ((bal >> lane) & 1ull) {
                    int pos = base + (int)__popcll(bal & lt);
                    if (pos < lim) {
                        float dx = cc ? dxB[r] : dxA[r];
                        float dy = cc ? dyB[r] : dyA[r];
                        float dz = cc ? dzB[r] : dzA[r];
                        float r2 = cc ? r2B[r] : r2A[r];
                        float rr = sqrtf(r2);
                        float rinv = __builtin_amdgcn_rcpf(rr);
                        float u  = rr * (1.0f / RCUT);
                        float u3 = u * u * u;
                        float sw_ = ((-6.0f * u + 15.0f) * u - 10.0f) * u3 + 1.0f;
                        float sr  = sw_ * rinv;
                        float crs = sr * rinv * ixrs + 1e-15f;
                        s_srn[pos]   = (sr - srm) * isrs;
                        s_cf[0][pos] = sr * isrs;
                        s_cf[1][pos] = crs * dx;
                        s_cf[2][pos] = crs * dy;
                        s_cf[3][pos] = crs * dz;
                        s_nbr[pos]   = (unsigned short)m;
                    }
                }
                if (cc) baseB += (int)__popcll(bal);
                else    baseA += (int)__popcll(bal);
            }
        }
    }
    __syncthreads();

    // ---- barrier-free per-wave chunk loop (16 pairs per chunk) ----
    const f4 zf4 = {0.0f, 0.0f, 0.0f, 0.0f};
    float gkA[4][4] = {}, gkB[4][4] = {};   // [k][nt], col = 16nt+l15, rows via lk

    for (int ch = wid; ch < nchunks; ch += 4) {
        const int base = ch << 4;
        const bool isB = base >= cntA_pad;

        // h0 a-frag: row = l15 (pair base+l15), k = 8lk+q
        float srn = s_srn[base + l15];
        int jrow = (s_nbr[base + l15] >= n1) ? 1 : 0;
        h8 a = {};
        if (lk < 2) {
            #pragma unroll
            for (int q = 0; q < 8; q++) {
                float wv = jrow ? (float)w0h[1][q] : (float)w0h[0][q];
                float bv = jrow ? (float)b0h[1][q] : (float)b0h[0][q];
                a[q] = (_Float16)fast_tanh(fmaf(srn, wv, bv));
            }
        }
        // row types for my 4 output rows (4lk+r)
        int j_r[4];
        #pragma unroll
        for (int r = 0; r < 4; r++)
            j_r[r] = (s_nbr[base + 4 * lk + r] >= n1) ? 1 : 0;

        // W1: h1[16][32]
        #pragma unroll
        for (int nt1 = 0; nt1 < 2; nt1++) {
            f4 d0 = __builtin_amdgcn_mfma_f32_16x16x32_f16(a, w1f[0][nt1], zf4, 0, 0, 0);
            f4 d1 = __builtin_amdgcn_mfma_f32_16x16x32_f16(a, w1f[1][nt1], zf4, 0, 0, 0);
            #pragma unroll
            for (int r = 0; r < 4; r++) {
                float dv = j_r[r] ? d1[r] : d0[r];
                float bv = j_r[r] ? b1r[1][nt1] : b1r[0][nt1];
                s_h1w[wid][4 * lk + r][16 * nt1 + l15] = (_Float16)fast_tanh(dv + bv);
            }
        }
        asm volatile("" ::: "memory");
        // W2 a-frag: row = l15, k = 8lk+q (same-wave LDS, in-order)
        h8 a2 = *(const h8*)&s_h1w[wid][l15][8 * lk];

        // coefs for my rows (prefetch before MFMAs)
        f4 cfv[4];
        #pragma unroll
        for (int k = 0; k < 4; k++)
            cfv[k] = *(const f4*)&s_cf[k][base + 4 * lk];

        // W2 + in-register accumulate
        #pragma unroll
        for (int nt = 0; nt < 4; nt++) {
            f4 e0 = __builtin_amdgcn_mfma_f32_16x16x32_f16(a2, w2f[0][nt], zf4, 0, 0, 0);
            f4 e1 = __builtin_amdgcn_mfma_f32_16x16x32_f16(a2, w2f[1][nt], zf4, 0, 0, 0);
            float ev[4];
            #pragma unroll
            for (int r = 0; r < 4; r++) {
                float dv = j_r[r] ? e1[r] : e0[r];
                float bv = j_r[r] ? b2r[1][nt] : b2r[0][nt];
                ev[r] = fast_tanh(dv + bv);
            }
            if (isB) {
                #pragma unroll
                for (int k = 0; k < 4; k++)
                    #pragma unroll
                    for (int r = 0; r < 4; r++)
                        gkB[k][nt] = fmaf(cfv[k][r], ev[r], gkB[k][nt]);
            } else {
                #pragma unroll
                for (int k = 0; k < 4; k++)
                    #pragma unroll
                    for (int r = 0; r < 4; r++)
                        gkA[k][nt] = fmaf(cfv[k][r], ev[r], gkA[k][nt]);
            }
        }
    }

    // ---- reduce over lk lanes (shuffles), then over waves (LDS) ----
    #pragma unroll
    for (int k = 0; k < 4; k++) {
        #pragma unroll
        for (int nt = 0; nt < 4; nt++) {
            float vA = gkA[k][nt], vB = gkB[k][nt];
            vA += __shfl_xor(vA, 16); vA += __shfl_xor(vA, 32);
            vB += __shfl_xor(vB, 16); vB += __shfl_xor(vB, 32);
            if (lane < 16) {
                s_gA[wid][k][nt * 16 + lane] = vA;
                s_gB[wid][k][nt * 16 + lane] = vB;
            }
        }
    }
    __syncthreads();
    #pragma unroll
    for (int it = 0; it < 2; it++) {
        int idx = tid + 256 * it;              // (at, k, c)
        int at = idx >> 8, k = (idx >> 6) & 3, c = idx & 63;
        const float (*sg)[4][64] = at ? s_gB : s_gA;
        float g = (sg[0][k][c] + sg[1][k][c]) + (sg[2][k][c] + sg[3][k][c]);
        g *= (1.0f / 64.0f);
        if (k == 0) g += Gbias[c];
        s_g4[at][k * 64 + c] = g;
    }
    __syncthreads();

    // ---- Feat epilogue (unchanged, verified) ----
    #pragma unroll
    for (int at = 0; at < 2; at++) {
        const float* sg = &s_g4[at][0];
        h2v* outp = feat + (size_t)(2 * nb + at) * 512;
        #pragma unroll
        for (int q = 0; q < 2; q++) {
            int o2 = tid + 256 * q;
            int aa = o2 >> 5, c = (2 * o2) & 63;
            float ga0 = sg[aa],       ga1 = sg[64 + aa];
            float ga2 = sg[128 + aa], ga3 = sg[192 + aa];
            float s0 = ga0 * sg[c];
            s0 = fmaf(ga1, sg[64 + c],  s0);
            s0 = fmaf(ga2, sg[128 + c], s0);
            s0 = fmaf(ga3, sg[192 + c], s0);
            float s1 = ga0 * sg[c + 1];
            s1 = fmaf(ga1, sg[64 + c + 1],  s1);
            s1 = fmaf(ga2, sg[128 + c + 1], s1);
            s1 = fmaf(ga3, sg[192 + c + 1], s1);
            outp[o2] = pkh(s0, s1);
        }
    }
}

// ---- Kernel 2: fit net, 64 blocks x 16 atoms, direct-from-L2 fragments ----
__global__ __launch_bounds__(512, 1) void k_fit(
    const _Float16* __restrict__ featf, const _Float16* __restrict__ W0ht,
    const _Float16* __restrict__ W1ht,
    const float* __restrict__ b0, const float* __restrict__ b1,
    const float* __restrict__ W2, const float* __restrict__ b2,
    const float* __restrict__ Ebias, const int* __restrict__ n1p,
    unsigned int* __restrict__ counter, float* __restrict__ slots,
    float* __restrict__ out)
{
    __shared__ float s_red[4][2][16][64];
    __shared__ __align__(16) _Float16 s_hd[16][128];
    __shared__ float s_sum[16][32];

    const int tid = threadIdx.x;
    const int lane = tid & 63, w = tid >> 6;
    const int kq = w >> 1, ch = w & 1;
    const int l15 = lane & 15, lk = lane >> 4;
    const int n0 = blockIdx.x * 16;
    const int ia = (n0 >= *n1p) ? 1 : 0;
    const f4 zf4 = {0.0f, 0.0f, 0.0f, 0.0f};

    const _Float16* Ap = featf + (size_t)(n0 + l15) * 1024 + kq * 256;
    const _Float16* B0 = W0ht + (size_t)ia * 131072 + kq * 256;
    f4 acc[4] = {zf4, zf4, zf4, zf4};
    #pragma unroll
    for (int ks = 0; ks < 8; ks++) {
        h8 a = *(const h8*)(Ap + ks * 32 + 8 * lk);
        #pragma unroll
        for (int nt = 0; nt < 4; nt++) {
            const int c = ch * 64 + nt * 16 + l15;
            h8 b = *(const h8*)(B0 + (size_t)c * 1024 + ks * 32 + 8 * lk);
            acc[nt] = __builtin_amdgcn_mfma_f32_16x16x32_f16(a, b, acc[nt], 0, 0, 0);
        }
    }
    #pragma unroll
    for (int nt = 0; nt < 4; nt++)
        #pragma unroll
        for (int r = 0; r < 4; r++)
            s_red[kq][ch][4 * lk + r][nt * 16 + l15] = acc[nt][r];
    __syncthreads();

    {
        const int row = tid >> 5, c0 = (tid & 31) * 4;
        const int chh = c0 >> 6, cl = c0 & 63;
        f4 v = *(const f4*)&s_red[0][chh][row][cl];
        v += *(const f4*)&s_red[1][chh][row][cl];
        v += *(const f4*)&s_red[2][chh][row][cl];
        v += *(const f4*)&s_red[3][chh][row][cl];
        #pragma unroll
        for (int q = 0; q < 4; q++) {
            int c = c0 + q;
            float h = fast_tanh(v[q] + b0[ia * 128 + c]);
            s_hd[row][(((c >> 3) ^ row) << 3) + (c & 7)] = (_Float16)h;
        }
    }
    __syncthreads();

    f4 acc1[4] = {zf4, zf4, zf4, zf4};
    {
        h8 a = *(const h8*)&s_hd[l15][(((4 * kq + lk) ^ l15) & 15) << 3];
        const _Float16* B1 = W1ht + (size_t)ia * 16384 + kq * 32;
        #pragma unroll
        for (int nt = 0; nt < 4; nt++) {
            const int c = ch * 64 + nt * 16 + l15;
            h8 b = *(const h8*)(B1 + (size_t)c * 128 + 8 * lk);
            acc1[nt] = __builtin_amdgcn_mfma_f32_16x16x32_f16(a, b, zf4, 0, 0, 0);
        }
    }
    #pragma unroll
    for (int nt = 0; nt < 4; nt++)
        #pragma unroll
        for (int r = 0; r < 4; r++)
            s_red[kq][ch][4 * lk + r][nt * 16 + l15] = acc1[nt][r];
    __syncthreads();

    {
        const int row = tid >> 5, c0 = (tid & 31) * 4;
        const int chh = c0 >> 6, cl = c0 & 63;
        f4 v = *(const f4*)&s_red[0][chh][row][cl];
        v += *(const f4*)&s_red[1][chh][row][cl];
        v += *(const f4*)&s_red[2][chh][row][cl];
        v += *(const f4*)&s_red[3][chh][row][cl];
        float pv = 0.0f;
        #pragma unroll
        for (int q = 0; q < 4; q++) {
            int c = c0 + q;
            pv += fast_tanh(v[q] + b1[ia * 128 + c]) * W2[ia * 128 + c];
        }
        s_sum[row][tid & 31] = pv;
    }
    __syncthreads();
    if (w == 0) {
        const int row = lane >> 2, g = lane & 3;
        float s = 0.0f;
        #pragma unroll
        for (int i = 0; i < 8; i++) s += s_sum[row][8 * g + i];
        s += __shfl_xor(s, 1);  s += __shfl_xor(s, 2);
        s += __shfl_xor(s, 4);  s += __shfl_xor(s, 8);
        s += __shfl_xor(s, 16); s += __shfl_xor(s, 32);
        if (lane == 0) {
            float e = s + 16.0f * (b2[ia] + Ebias[ia]);
            slots[blockIdx.x] = e;
            __threadfence();
            unsigned int old = atomicAdd(counter, 1u);
            if (old == 63u) {
                __threadfence();
                float tot = 0.0f;
                for (int i = 0; i < 64; i++)
                    tot += __hip_atomic_load(&slots[i], __ATOMIC_RELAXED, __HIP_MEMORY_SCOPE_AGENT);
                out[0] = tot;
            }
        }
    }
}

extern "C" void kernel_launch(void* const* d_in, const int* in_sizes, int n_in,
                              void* d_out, int out_size, void* d_ws, size_t ws_size,
                              hipStream_t stream) {
    const float* coord   = (const float*)d_in[0];
    const float* box     = (const float*)d_in[1];
    const float* srmean  = (const float*)d_in[2];
    const float* srstd   = (const float*)d_in[3];
    const float* xrsrstd = (const float*)d_in[4];
    const float* Gbias   = (const float*)d_in[5];
    const float* Ebias   = (const float*)d_in[6];
    const float* eW0     = (const float*)d_in[7];
    const float* eb0     = (const float*)d_in[8];
    const float* eW1     = (const float*)d_in[9];
    const float* eb1     = (const float*)d_in[10];
    const float* eW2     = (const float*)d_in[11];
    const float* eb2     = (const float*)d_in[12];
    const float* fW0     = (const float*)d_in[13];
    const float* fb0     = (const float*)d_in[14];
    const float* fW1     = (const float*)d_in[15];
    const float* fb1     = (const float*)d_in[16];
    const float* fW2     = (const float*)d_in[17];
    const float* fb2     = (const float*)d_in[18];
    const int*   n1p     = (const int*)d_in[19];

    const int N = in_sizes[0] / 3;          // 1024
    h2v*      featbuf = (h2v*)d_ws;                                       // 2 MB
    _Float16* W0ht = (_Float16*)((char*)d_ws + (size_t)2 * 1024 * 1024);  // 512 KB
    _Float16* W1ht = W0ht + 2 * 131072;                                   // 64 KB
    char* tail = (char*)d_ws + (size_t)(2 * 1024 + 512 + 64) * 1024;
    unsigned int* counter = (unsigned int*)tail;
    float*        slots   = (float*)(tail + 64);

    k_embed<<<N / 2 + 288, 256, 0, stream>>>(coord, box, srmean, srstd, xrsrstd,
                                             Gbias, eW0, eb0, eW1, eb1, eW2, eb2,
                                             n1p, fW0, fW1, featbuf, W0ht, W1ht,
                                             counter, N);
    k_fit<<<N / 16, 512, 0, stream>>>((const _Float16*)featbuf, W0ht, W1ht,
                                      fb0, fb1, fW2, fb2, Ebias, n1p,
                                      counter, slots, (float*)d_out);
}

// Round 11
// 39.369 us; speedup vs baseline: 1.0861x; 1.0861x over previous
//
#include <hip/hip_runtime.h>

#define RCUT 6.0f

typedef _Float16 h2v __attribute__((ext_vector_type(2)));
typedef _Float16 h8  __attribute__((ext_vector_type(8)));
typedef float    f4  __attribute__((ext_vector_type(4)));

__device__ __forceinline__ float fast_tanh(float x) {
    float e = __expf(2.0f * x);              // inf for large x -> tanh=1
    return 1.0f - 2.0f * __builtin_amdgcn_rcpf(e + 1.0f);
}

__device__ __forceinline__ h2v pkh(float a, float b) {
#if __has_builtin(__builtin_amdgcn_cvt_pkrtz)
    union { __fp16 __attribute__((ext_vector_type(2))) r; h2v h; } u;
    u.r = __builtin_amdgcn_cvt_pkrtz(a, b);
    return u.h;
#else
    h2v r; r.x = (_Float16)a; r.y = (_Float16)b; return r;
#endif
}

// ---- Kernel 1: 2 atoms/block; scan precomputes coefs; W1+W2+stage2 MFMA ----
// Blocks [0, NB): atom pair (2b, 2b+1). Blocks [NB, NB+288): fit-weight prep.
// launch_bounds (256,2): 256-VGPR cap -> NO SPILL; 2 blocks/CU covers grid.
__global__ __launch_bounds__(256, 2) void k_embed(
    const float* __restrict__ coord, const float* __restrict__ box,
    const float* __restrict__ srmean, const float* __restrict__ srstd,
    const float* __restrict__ xrsrstd, const float* __restrict__ Gbias,
    const float* __restrict__ eW0, const float* __restrict__ eb0,
    const float* __restrict__ eW1, const float* __restrict__ eb1,
    const float* __restrict__ eW2, const float* __restrict__ eb2,
    const int* __restrict__ n1p,
    const float* __restrict__ fW0, const float* __restrict__ fW1,
    h2v* __restrict__ feat, _Float16* __restrict__ W0ht,
    _Float16* __restrict__ W1ht, unsigned int* __restrict__ counter, int N)
{
    const int nb  = blockIdx.x;
    const int tid = threadIdx.x;
    const int NB  = N >> 1;

    __shared__ float s_w0[2][16], s_b0[2][16];
    __shared__ __align__(16) _Float16 s_srn[1024];      // 2 KB
    __shared__ __align__(16) _Float16 s_cf[4][1024];    // 8 KB  per-pair coefs
    __shared__ __align__(16) _Float16 s_h1[128][32];    // 8 KB  (XOR-swizzled units)
    __shared__ __align__(16) _Float16 s_ef[4][4][64][8];// 16 KB e in B-frag layout
    __shared__ unsigned short s_nbr[1024];              // 2 KB
    __shared__ float s_g4[2][256];                      // 2 KB  G for both atoms
    __shared__ __align__(16) _Float16 w1t[2][32][24];   // 3 KB  [j][c][k(16)+pad]
    __shared__ __align__(16) _Float16 w2t[2][64][40];   // 10 KB [j][c][k(32)+pad]
    __shared__ int s_wA[4], s_wB[4];

    // ================= prep path: transpose+fp16 fit weights =================
    if (nb >= NB) {
        const int b = nb - NB;
        if (b == 0 && tid == 0) *counter = 0u;
        float (*s_t)[33] = reinterpret_cast<float(*)[33]>(&s_ef[0][0][0][0]);
        if (b < 256) {
            int type = b >> 7, tb = b & 127;
            int ki = tb >> 2, ci = tb & 3;
            const float* src = fW0 + (size_t)type * 131072;
            int c = tid & 31, r0 = (tid >> 5) * 4;
            #pragma unroll
            for (int q = 0; q < 4; q++)
                s_t[r0 + q][c] = src[(size_t)(ki * 32 + r0 + q) * 128 + ci * 32 + c];
            __syncthreads();
            _Float16* dst = W0ht + (size_t)type * 131072;
            int kk = tid & 31, c0 = (tid >> 5) * 4;
            #pragma unroll
            for (int q = 0; q < 4; q++)
                dst[(size_t)(ci * 32 + c0 + q) * 1024 + ki * 32 + kk] = (_Float16)s_t[kk][c0 + q];
        } else {
            int b2v = b - 256, type = b2v >> 4, tb = b2v & 15;
            int ki = tb >> 2, ci = tb & 3;
            const float* src = fW1 + (size_t)type * 16384;
            int c = tid & 31, r0 = (tid >> 5) * 4;
            #pragma unroll
            for (int q = 0; q < 4; q++)
                s_t[r0 + q][c] = src[(size_t)(ki * 32 + r0 + q) * 128 + ci * 32 + c];
            __syncthreads();
            _Float16* dst = W1ht + (size_t)type * 16384;
            int kk = tid & 31, c0 = (tid >> 5) * 4;
            #pragma unroll
            for (int q = 0; q < 4; q++)
                dst[(size_t)(ci * 32 + c0 + q) * 128 + ki * 32 + kk] = (_Float16)s_t[kk][c0 + q];
        }
        return;
    }

    // ================= main path =================
    const int nA = 2 * nb, nBt = 2 * nb + 1;
    const int n1 = *n1p;
    const int ti = (nA >= n1) ? 1 : 0;
    const int wid = tid >> 6, lane = tid & 63;
    const int l15 = lane & 15, lk = lane >> 4;

    // ---- coalesced weight staging into LDS ----
    for (int t = tid; t < 32; t += 256) { int j = t >> 4, f = t & 15;
        s_w0[j][f] = eW0[(2 * ti + j) * 16 + f];
        s_b0[j][f] = eb0[(2 * ti + j) * 16 + f]; }
    for (int idx = tid; idx < 1024; idx += 256) {        // W1: [j][g(c)][f(k)]
        int j = idx >> 9, r = idx & 511, f = r >> 5, g = r & 31;
        w1t[j][g][f] = (_Float16)eW1[(2 * ti + j) * 512 + f * 32 + g];
    }
    for (int idx = tid; idx < 4096; idx += 256) {        // W2: [j][c][g(k)]
        int j = idx >> 11, r = idx & 2047, g = r >> 6, c = r & 63;
        w2t[j][c][g] = (_Float16)eW2[(2 * ti + j) * 2048 + g * 64 + c];
    }
    // per-lane bias registers
    float b1r[2][2], b2r[2][4];
    #pragma unroll
    for (int j = 0; j < 2; j++) {
        #pragma unroll
        for (int q = 0; q < 2; q++) b1r[j][q] = eb1[(2 * ti + j) * 32 + 16 * q + l15];
        #pragma unroll
        for (int q = 0; q < 4; q++) b2r[j][q] = eb2[(2 * ti + j) * 64 + 16 * q + l15];
    }

    const float Lx = box[0], Ly = box[4], Lz = box[8];
    const float iLx = 1.0f / Lx, iLy = 1.0f / Ly, iLz = 1.0f / Lz;
    const float xA = coord[nA], yA = coord[N + nA], zA = coord[2 * N + nA];
    const float xB = coord[nBt], yB = coord[N + nBt], zB = coord[2 * N + nBt];
    const float srm  = srmean[ti];
    const float isrs = 1.0f / srstd[ti];
    const float ixrs = 1.0f / xrsrstd[ti];

    // ---- dual-center scan: pass 1 = ballots only (no saved geometry) ----
    unsigned long long balA[4], balB[4];
    {
        int wA = 0, wB = 0;
        const int mystart = wid * 256;
        #pragma unroll
        for (int r = 0; r < 4; r++) {
            int m = mystart + r * 64 + lane;
            float x = coord[m], y = coord[N + m], z = coord[2 * N + m];
            float ax = x - xA; ax -= Lx * rintf(ax * iLx);
            float ay = y - yA; ay -= Ly * rintf(ay * iLy);
            float az = z - zA; az -= Lz * rintf(az * iLz);
            float ra = ax * ax + ay * ay + az * az;
            float bx = x - xB; bx -= Lx * rintf(bx * iLx);
            float by = y - yB; by -= Ly * rintf(by * iLy);
            float bz = z - zB; bz -= Lz * rintf(bz * iLz);
            float rb = bx * bx + by * by + bz * bz;
            bool pA = (ra < RCUT * RCUT) && (m != nA);
            bool pB = (rb < RCUT * RCUT) && (m != nBt);
            balA[r] = __ballot(pA);
            balB[r] = __ballot(pB);
            wA += (int)__popcll(balA[r]);
            wB += (int)__popcll(balB[r]);
        }
        if (lane == 0) { s_wA[wid] = wA; s_wB[wid] = wB; }
    }
    __syncthreads();
    int cntA = s_wA[0] + s_wA[1] + s_wA[2] + s_wA[3];
    int cntB = s_wB[0] + s_wB[1] + s_wB[2] + s_wB[3];
    int cnt  = cntA + cntB;
    if (cnt > 1024) cnt = 1024;
    if (cntA > 1024) cntA = 1024;
    {
        int baseA = 0, baseB = cntA;
        for (int w = 0; w < wid; w++) { baseA += s_wA[w]; baseB += s_wB[w]; }
        const unsigned long long lt = (1ull << lane) - 1ull;
        const int mystart = wid * 256;
        #pragma unroll
        for (int r = 0; r < 4; r++) {
            int m = mystart + r * 64 + lane;
            float x = coord[m], y = coord[N + m], z = coord[2 * N + m];
            #pragma unroll
            for (int cc = 0; cc < 2; cc++) {
                unsigned long long bal = cc ? balB[r] : balA[r];
                int base = cc ? baseB : baseA;
                if ((bal >> lane) & 1ull) {
                    int pos = base + (int)__popcll(bal & lt);
                    if (pos < 1024) {
                        float dx = x - (cc ? xB : xA); dx -= Lx * rintf(dx * iLx);
                        float dy = y - (cc ? yB : yA); dy -= Ly * rintf(dy * iLy);
                        float dz = z - (cc ? zB : zA); dz -= Lz * rintf(dz * iLz);
                        float r2 = dx * dx + dy * dy + dz * dz;
                        float rr = sqrtf(r2);
                        float rinv = __builtin_amdgcn_rcpf(rr);
                        float u  = rr * (1.0f / RCUT);
                        float u3 = u * u * u;
                        float sw_ = ((-6.0f * u + 15.0f) * u - 10.0f) * u3 + 1.0f;
                        float sr  = sw_ * rinv;
                        float crs = sr * rinv * ixrs + 1e-15f;
                        s_srn[pos]   = (_Float16)((sr - srm) * isrs);
                        s_cf[0][pos] = (_Float16)(sr * isrs);
                        s_cf[1][pos] = (_Float16)(crs * dx);
                        s_cf[2][pos] = (_Float16)(crs * dy);
                        s_cf[3][pos] = (_Float16)(crs * dz);
                        s_nbr[pos]   = (unsigned short)m;
                    }
                }
                if (cc) baseB += (int)__popcll(bal);
                else    baseA += (int)__popcll(bal);
            }
        }
    }
    __syncthreads();
    const int ntiles = (cnt + 127) >> 7;
    // zero the tail so tail pairs yield finite e and zero coef
    for (int i = cnt + tid; i < ntiles * 128; i += 256) {
        s_srn[i] = (_Float16)0.0f; s_nbr[i] = 0;
        s_cf[0][i] = (_Float16)0.0f; s_cf[1][i] = (_Float16)0.0f;
        s_cf[2][i] = (_Float16)0.0f; s_cf[3][i] = (_Float16)0.0f;
    }
    __syncthreads();

    f4 gacc = {0.0f, 0.0f, 0.0f, 0.0f};
    const f4 zf4 = {0.0f, 0.0f, 0.0f, 0.0f};

    for (int t = 0; t < ntiles; t++) {
        const int t128 = t << 7;
        __syncthreads();   // B1: protect s_ef from previous stage-2 readers

        // ---- W1 (h0 inline) then W2, fused per wave (same-wave LDS deps) ----
        #pragma unroll
        for (int mt2 = 0; mt2 < 2; mt2++) {
            const int mt = 2 * wid + mt2;
            const int row = 16 * mt + l15;
            const int rp = t128 + row;
            float srn = (float)s_srn[rp];
            int jr = (s_nbr[rp] >= n1) ? 1 : 0;
            h8 a = {};
            if (lk < 2) {
                const float* wp = &s_w0[jr][8 * lk];
                const float* bp = &s_b0[jr][8 * lk];
                #pragma unroll
                for (int q = 0; q < 8; q++)
                    a[q] = (_Float16)fast_tanh(fmaf(srn, wp[q], bp[q]));
            }
            #pragma unroll
            for (int nt1 = 0; nt1 < 2; nt1++) {
                const int c = 16 * nt1 + l15;
                h8 b0f = {}, b1f = {};
                if (lk < 2) {
                    b0f = *(const h8*)&w1t[0][c][8 * lk];
                    b1f = *(const h8*)&w1t[1][c][8 * lk];
                }
                f4 d0 = __builtin_amdgcn_mfma_f32_16x16x32_f16(a, b0f, zf4, 0, 0, 0);
                f4 d1 = __builtin_amdgcn_mfma_f32_16x16x32_f16(a, b1f, zf4, 0, 0, 0);
                #pragma unroll
                for (int r = 0; r < 4; r++) {
                    int gp = 16 * mt + 4 * lk + r;
                    bool is0 = (s_nbr[t128 + gp] < n1);
                    float hv = fast_tanh((is0 ? d0[r] : d1[r]) + (is0 ? b1r[0][nt1] : b1r[1][nt1]));
                    int e = 16 * nt1 + l15;
                    s_h1[gp][(((e >> 3) ^ ((gp >> 1) & 3)) << 3) + (e & 7)] = (_Float16)hv;
                }
            }
        }
        asm volatile("" ::: "memory");   // keep W2 reads after W1 writes
        #pragma unroll
        for (int mt2 = 0; mt2 < 2; mt2++) {
            const int mt = 2 * wid + mt2;
            const int row = 16 * mt + l15;
            h8 a2 = *(const h8*)&s_h1[row][((lk ^ ((row >> 1) & 3)) << 3)];
            #pragma unroll
            for (int nt = 0; nt < 4; nt++) {
                const int c = 16 * nt + l15;
                h8 w20 = *(const h8*)&w2t[0][c][8 * lk];
                h8 w21 = *(const h8*)&w2t[1][c][8 * lk];
                f4 e0 = __builtin_amdgcn_mfma_f32_16x16x32_f16(a2, w20, zf4, 0, 0, 0);
                f4 e1 = __builtin_amdgcn_mfma_f32_16x16x32_f16(a2, w21, zf4, 0, 0, 0);
                #pragma unroll
                for (int r = 0; r < 4; r++) {
                    int gp = 16 * mt + 4 * lk + r;
                    bool is0 = (s_nbr[t128 + gp] < n1);
                    float ev = fast_tanh((is0 ? e0[r] : e1[r]) + (is0 ? b2r[0][nt] : b2r[1][nt]));
                    s_ef[nt][gp >> 5][l15 + 16 * ((gp & 31) >> 3)][gp & 7] = (_Float16)ev;
                }
            }
        }
        __syncthreads();   // B3: s_ef ready (cross-wave)

        // ---- stage 2: G[8pad16][64] += coef[8][128] @ e[128][64] ----
        // coef rows 0-3 = atom A, rows 4-7 = atom B (list is [A-pairs | B-pairs])
        #pragma unroll
        for (int ks = 0; ks < 4; ks++) {
            const int s = t128 + 32 * ks;
            h8 ac = {};
            if (l15 < 8) {
                const bool rowA = l15 < 4;
                const int  cr   = rowA ? l15 : (l15 - 4);
                const bool allA = (s + 31) < cntA;
                const bool allB = s >= cntA;
                if ((allA && rowA) || (allB && !rowA)) {
                    ac = *(const h8*)&s_cf[cr][s + 8 * lk];
                } else if (!allA && !allB) {
                    #pragma unroll
                    for (int r = 0; r < 8; r++) {
                        int p = s + 8 * lk + r;
                        bool isA = p < cntA;
                        if (isA == rowA) ac[r] = s_cf[cr][p];
                    }
                }
            }
            h8 eb = *(const h8*)&s_ef[wid][ks][lane][0];
            gacc = __builtin_amdgcn_mfma_f32_16x16x32_f16(ac, eb, gacc, 0, 0, 0);
        }
    }

    // ---- epilogue: rows 0-3 (lk=0) = atom A, rows 4-7 (lk=1) = atom B ----
    if (lk < 2) {
        float* sg = &s_g4[lk][0];
        #pragma unroll
        for (int r = 0; r < 4; r++) {
            float gv = gacc[r] * (1.0f / 64.0f);
            if (r == 0) gv += Gbias[16 * wid + l15];
            sg[r * 64 + 16 * wid + l15] = gv;
        }
    }
    __syncthreads();
    #pragma unroll
    for (int at = 0; at < 2; at++) {
        const float* sg = &s_g4[at][0];
        h2v* outp = feat + (size_t)(2 * nb + at) * 512;
        #pragma unroll
        for (int q = 0; q < 2; q++) {
            int o2 = tid + 256 * q;
            int a = o2 >> 5, c = (2 * o2) & 63;
            float ga0 = sg[a],       ga1 = sg[64 + a];
            float ga2 = sg[128 + a], ga3 = sg[192 + a];
            float s0 = ga0 * sg[c];
            s0 = fmaf(ga1, sg[64 + c],  s0);
            s0 = fmaf(ga2, sg[128 + c], s0);
            s0 = fmaf(ga3, sg[192 + c], s0);
            float s1 = ga0 * sg[c + 1];
            s1 = fmaf(ga1, sg[64 + c + 1],  s1);
            s1 = fmaf(ga2, sg[128 + c + 1], s1);
            s1 = fmaf(ga3, sg[192 + c + 1], s1);
            outp[o2] = pkh(s0, s1);
        }
    }
}

// ---- Kernel 2: fit net, 64 blocks x 16 atoms, direct-from-L2 fragments ----
__global__ __launch_bounds__(512) void k_fit(
    const _Float16* __restrict__ featf, const _Float16* __restrict__ W0ht,
    const _Float16* __restrict__ W1ht,
    const float* __restrict__ b0, const float* __restrict__ b1,
    const float* __restrict__ W2, const float* __restrict__ b2,
    const float* __restrict__ Ebias, const int* __restrict__ n1p,
    unsigned int* __restrict__ counter, float* __restrict__ slots,
    float* __restrict__ out)
{
    __shared__ float s_red[4][2][16][64];
    __shared__ __align__(16) _Float16 s_hd[16][128];
    __shared__ float s_sum[16][32];

    const int tid = threadIdx.x;
    const int lane = tid & 63, w = tid >> 6;
    const int kq = w >> 1, ch = w & 1;
    const int l15 = lane & 15, lk = lane >> 4;
    const int n0 = blockIdx.x * 16;
    const int ia = (n0 >= *n1p) ? 1 : 0;
    const f4 zf4 = {0.0f, 0.0f, 0.0f, 0.0f};

    const _Float16* Ap = featf + (size_t)(n0 + l15) * 1024 + kq * 256;
    const _Float16* B0 = W0ht + (size_t)ia * 131072 + kq * 256;
    f4 acc[4] = {zf4, zf4, zf4, zf4};
    #pragma unroll
    for (int ks = 0; ks < 8; ks++) {
        h8 a = *(const h8*)(Ap + ks * 32 + 8 * lk);
        #pragma unroll
        for (int nt = 0; nt < 4; nt++) {
            const int c = ch * 64 + nt * 16 + l15;
            h8 b = *(const h8*)(B0 + (size_t)c * 1024 + ks * 32 + 8 * lk);
            acc[nt] = __builtin_amdgcn_mfma_f32_16x16x32_f16(a, b, acc[nt], 0, 0, 0);
        }
    }
    #pragma unroll
    for (int nt = 0; nt < 4; nt++)
        #pragma unroll
        for (int r = 0; r < 4; r++)
            s_red[kq][ch][4 * lk + r][nt * 16 + l15] = acc[nt][r];
    __syncthreads();

    {
        const int row = tid >> 5, c0 = (tid & 31) * 4;
        const int chh = c0 >> 6, cl = c0 & 63;
        f4 v = *(const f4*)&s_red[0][chh][row][cl];
        v += *(const f4*)&s_red[1][chh][row][cl];
        v += *(const f4*)&s_red[2][chh][row][cl];
        v += *(const f4*)&s_red[3][chh][row][cl];
        #pragma unroll
        for (int q = 0; q < 4; q++) {
            int c = c0 + q;
            float h = fast_tanh(v[q] + b0[ia * 128 + c]);
            s_hd[row][(((c >> 3) ^ row) << 3) + (c & 7)] = (_Float16)h;
        }
    }
    __syncthreads();

    f4 acc1[4] = {zf4, zf4, zf4, zf4};
    {
        h8 a = *(const h8*)&s_hd[l15][(((4 * kq + lk) ^ l15) & 15) << 3];
        const _Float16* B1 = W1ht + (size_t)ia * 16384 + kq * 32;
        #pragma unroll
        for (int nt = 0; nt < 4; nt++) {
            const int c = ch * 64 + nt * 16 + l15;
            h8 b = *(const h8*)(B1 + (size_t)c * 128 + 8 * lk);
            acc1[nt] = __builtin_amdgcn_mfma_f32_16x16x32_f16(a, b, zf4, 0, 0, 0);
        }
    }
    #pragma unroll
    for (int nt = 0; nt < 4; nt++)
        #pragma unroll
        for (int r = 0; r < 4; r++)
            s_red[kq][ch][4 * lk + r][nt * 16 + l15] = acc1[nt][r];
    __syncthreads();

    {
        const int row = tid >> 5, c0 = (tid & 31) * 4;
        const int chh = c0 >> 6, cl = c0 & 63;
        f4 v = *(const f4*)&s_red[0][chh][row][cl];
        v += *(const f4*)&s_red[1][chh][row][cl];
        v += *(const f4*)&s_red[2][chh][row][cl];
        v += *(const f4*)&s_red[3][chh][row][cl];
        float pv = 0.0f;
        #pragma unroll
        for (int q = 0; q < 4; q++) {
            int c = c0 + q;
            pv += fast_tanh(v[q] + b1[ia * 128 + c]) * W2[ia * 128 + c];
        }
        s_sum[row][tid & 31] = pv;
    }
    __syncthreads();
    if (w == 0) {
        const int row = lane >> 2, g = lane & 3;
        float s = 0.0f;
        #pragma unroll
        for (int i = 0; i < 8; i++) s += s_sum[row][8 * g + i];
        s += __shfl_xor(s, 1);  s += __shfl_xor(s, 2);
        s += __shfl_xor(s, 4);  s += __shfl_xor(s, 8);
        s += __shfl_xor(s, 16); s += __shfl_xor(s, 32);
        if (lane == 0) {
            float e = s + 16.0f * (b2[ia] + Ebias[ia]);
            slots[blockIdx.x] = e;
            __threadfence();
            unsigned int old = atomicAdd(counter, 1u);
            if (old == 63u) {
                __threadfence();
                float tot = 0.0f;
                for (int i = 0; i < 64; i++)
                    tot += __hip_atomic_load(&slots[i], __ATOMIC_RELAXED, __HIP_MEMORY_SCOPE_AGENT);
                out[0] = tot;
            }
        }
    }
}

extern "C" void kernel_launch(void* const* d_in, const int* in_sizes, int n_in,
                              void* d_out, int out_size, void* d_ws, size_t ws_size,
                              hipStream_t stream) {
    const float* coord   = (const float*)d_in[0];
    const float* box     = (const float*)d_in[1];
    const float* srmean  = (const float*)d_in[2];
    const float* srstd   = (const float*)d_in[3];
    const float* xrsrstd = (const float*)d_in[4];
    const float* Gbias   = (const float*)d_in[5];
    const float* Ebias   = (const float*)d_in[6];
    const float* eW0     = (const float*)d_in[7];
    const float* eb0     = (const float*)d_in[8];
    const float* eW1     = (const float*)d_in[9];
    const float* eb1     = (const float*)d_in[10];
    const float* eW2     = (const float*)d_in[11];
    const float* eb2     = (const float*)d_in[12];
    const float* fW0     = (const float*)d_in[13];
    const float* fb0     = (const float*)d_in[14];
    const float* fW1     = (const float*)d_in[15];
    const float* fb1     = (const float*)d_in[16];
    const float* fW2     = (const float*)d_in[17];
    const float* fb2     = (const float*)d_in[18];
    const int*   n1p     = (const int*)d_in[19];

    const int N = in_sizes[0] / 3;          // 1024
    h2v*      featbuf = (h2v*)d_ws;                                       // 2 MB
    _Float16* W0ht = (_Float16*)((char*)d_ws + (size_t)2 * 1024 * 1024);  // 512 KB
    _Float16* W1ht = W0ht + 2 * 131072;                                   // 64 KB
    char* tail = (char*)d_ws + (size_t)(2 * 1024 + 512 + 64) * 1024;
    unsigned int* counter = (unsigned int*)tail;
    float*        slots   = (float*)(tail + 64);

    k_embed<<<N / 2 + 288, 256, 0, stream>>>(coord, box, srmean, srstd, xrsrstd,
                                             Gbias, eW0, eb0, eW1, eb1, eW2, eb2,
                                             n1p, fW0, fW1, featbuf, W0ht, W1ht,
                                             counter, N);
    k_fit<<<N / 16, 512, 0, stream>>>((const _Float16*)featbuf, W0ht, W1ht,
                                      fb0, fb1, fW2, fb2, Ebias, n1p,
                                      counter, slots, (float*)d_out);
}